// Round 8
// baseline (152.981 us; speedup 1.0000x reference)
//
#include <hip/hip_runtime.h>

// SAGEConv: h[50000,64] f32, src/dst[800000] int32, W[128,64] f32, b[64] f32
// out = concat(h, mean_{in-edges}(h[src])) @ W + b
//
// R8: 3 GPU ops (memset 3KB, prep, fused).
//  - Fixed-capacity buckets (64 nodes, CAP=2048 pairs, mean 1024) remove
//    hist+scan dispatches; per-tile LDS counts -> 1 global atomic per
//    (tile,bucket) reservation; writes clamped to CAP for memory safety.
//  - prep = h->bf16 convert + edge bucketing (disjoint block ranges).
//  - fused = per-bucket local CSR build in LDS (count/scan/scatter) +
//    read-side shfl-reduce gather (bf16 rows) + [h,h_N]@W+b MLP.
//  R7 lesson kept: read-side reduction, never write-side atomics.

#define IN_FEAT 64
#define KB_SHIFT 6            // 64 nodes per bucket
#define BKN 64
#define CAP 2048              // pairs per bucket (mean 1024 at E=800k,K=782)
#define KMAX 1024             // supports n_nodes <= 65536

__device__ __forceinline__ unsigned short f2bf(float f) {
    unsigned u = __float_as_uint(f);
    return (unsigned short)((u + 0x7FFFu + ((u >> 16) & 1u)) >> 16);
}
__device__ __forceinline__ float bf2f(unsigned short s) {
    return __uint_as_float(((unsigned)s) << 16);
}

// ---- k1: blocks [0,conv_tiles): h->bf16 ; rest: bucket the edges -----------
__global__ __launch_bounds__(256) void sage_prep(
    const float* __restrict__ h, const int* __restrict__ src,
    const int* __restrict__ dst,
    unsigned short* __restrict__ hb, unsigned* __restrict__ pairs,
    int* __restrict__ cursorG,
    int n4, int n_edges, int conv_tiles, int K)
{
    __shared__ int cnt[KMAX];
    __shared__ int base[KMAX];
    __shared__ int rnk[KMAX];
    int t = (int)threadIdx.x;

    if ((int)blockIdx.x < conv_tiles) {
        int tb = blockIdx.x * 8192;
        #pragma unroll
        for (int i = 0; i < 32; ++i) {
            int idx = tb + t + i * 256;            // float4 index
            if (idx < n4) {
                float4 v = ((const float4*)h)[idx];
                ushort4 r;
                r.x = f2bf(v.x); r.y = f2bf(v.y);
                r.z = f2bf(v.z); r.w = f2bf(v.w);
                ((ushort4*)hb)[idx] = r;
            }
        }
    } else {
        for (int k = t; k < K; k += 256) { cnt[k] = 0; rnk[k] = 0; }
        __syncthreads();
        int tb = ((int)blockIdx.x - conv_tiles) * 8192;
        #pragma unroll 8
        for (int i = 0; i < 32; ++i) {
            int e = tb + t + i * 256;
            if (e < n_edges) atomicAdd(&cnt[dst[e] >> KB_SHIFT], 1);
        }
        __syncthreads();
        for (int k = t; k < K; k += 256) {
            int c = cnt[k];
            base[k] = c ? atomicAdd(&cursorG[k], c) : 0;
        }
        __syncthreads();
        #pragma unroll 8
        for (int i = 0; i < 32; ++i) {
            int e = tb + t + i * 256;
            if (e < n_edges) {
                int d = dst[e];
                int k = d >> KB_SHIFT;
                int r = atomicAdd(&rnk[k], 1);
                int pos = base[k] + r;
                if (pos < CAP)                      // safety clamp
                    pairs[((size_t)k << 11) + pos] =
                        ((unsigned)src[e] << KB_SHIFT) | (unsigned)(d & (BKN - 1));
            }
        }
    }
}

// ---- k2: per-bucket local CSR + gather-mean + MLP --------------------------
// One block (512 thr, 8 waves) per 64-node bucket.
//  A: LDS CSR build: count per node, wave-0 scan, LDS cursor scatter.
//  B: wave w gathers nodes w*8..w*8+7: 16 lanes/edge x bf16x4 rows, 2x
//     unroll, __shfl_xor(16,32) reduce, mean -> hn (pad 68: 16B-aligned).
//  C: MLP: wave w, pass p: node w*8+p*4+sub, cols 4q..4q+3; self row f32
//     from global (broadcast), W rows ds_read_b128 shared by 4 nodes.
__global__ __launch_bounds__(512, 4) void sage_fused(
    const unsigned short* __restrict__ hb,
    const float* __restrict__ h,
    const unsigned* __restrict__ pairs,
    const int* __restrict__ cursorG,
    const float* __restrict__ W,     // [128,64] row-major
    const float* __restrict__ bias,
    float* __restrict__ out,
    int n_nodes)
{
    __shared__ float Wsh[128][64];   // 32 KB
    __shared__ float bsh[64];
    __shared__ float hn[BKN][68];    // 17.4 KB
    __shared__ int   list[CAP];      // 8 KB
    __shared__ int   cnt[BKN], rs[BKN + 1], cur[BKN];
    // total ~58.5 KB -> 2 blocks/CU (16 waves)

    const int t = (int)threadIdx.x;
    {   // stage W: 2048 float4s, 4 per thread
        float4* wd = (float4*)&Wsh[0][0];
        const float4* wsv = (const float4*)W;
        wd[t]        = wsv[t];
        wd[t + 512]  = wsv[t + 512];
        wd[t + 1024] = wsv[t + 1024];
        wd[t + 1536] = wsv[t + 1536];
    }
    if (t < 64) bsh[t] = bias[t];
    if (t < BKN) cnt[t] = 0;
    __syncthreads();

    const int b   = (int)blockIdx.x;
    const int nlo = b << KB_SHIFT;
    int m = cursorG[b]; if (m > CAP) m = CAP;
    const unsigned* pb = pairs + ((size_t)b << 11);

    // A1: per-node counts
    for (int i = t; i < m; i += 512) atomicAdd(&cnt[pb[i] & (BKN - 1)], 1);
    __syncthreads();
    // A2: wave 0 scans the 64 counters
    if (t < 64) {
        int v = cnt[t];
        int incl = v;
        #pragma unroll
        for (int off = 1; off < 64; off <<= 1) {
            int x = __shfl_up(incl, off);
            if (t >= off) incl += x;
        }
        rs[t] = incl - v;
        cur[t] = incl - v;
        if (t == 63) rs[64] = incl;
    }
    __syncthreads();
    // A3: scatter src ids into the node-sorted LDS list
    for (int i = t; i < m; i += 512) {
        unsigned p = pb[i];
        int pos = atomicAdd(&cur[p & (BKN - 1)], 1);
        list[pos] = (int)(p >> KB_SHIFT);
    }
    __syncthreads();

    const int w    = t >> 6;
    const int lane = t & 63;
    const int sub  = lane >> 4;
    const int q    = lane & 15;

    // B: gather — wave w owns nodes w*8..w*8+7
    #pragma unroll 2
    for (int i = 0; i < 8; ++i) {
        int nl = w * 8 + i;
        int n  = nlo + nl;
        if (n >= n_nodes) break;               // wave-uniform
        int beg = rs[nl], end = rs[nl + 1];
        float4 acc = make_float4(0.f, 0.f, 0.f, 0.f);
        int e = beg + sub;
        for (; e + 4 < end; e += 8) {
            int s0 = list[e], s1 = list[e + 4];
            const ushort4 u0 = *(const ushort4*)(hb + ((size_t)s0 << 6) + q * 4);
            const ushort4 u1 = *(const ushort4*)(hb + ((size_t)s1 << 6) + q * 4);
            acc.x += bf2f(u0.x) + bf2f(u1.x);
            acc.y += bf2f(u0.y) + bf2f(u1.y);
            acc.z += bf2f(u0.z) + bf2f(u1.z);
            acc.w += bf2f(u0.w) + bf2f(u1.w);
        }
        if (e < end) {
            int s0 = list[e];
            const ushort4 u0 = *(const ushort4*)(hb + ((size_t)s0 << 6) + q * 4);
            acc.x += bf2f(u0.x); acc.y += bf2f(u0.y);
            acc.z += bf2f(u0.z); acc.w += bf2f(u0.w);
        }
        #pragma unroll
        for (int mm = 16; mm < 64; mm <<= 1) {
            acc.x += __shfl_xor(acc.x, mm);
            acc.y += __shfl_xor(acc.y, mm);
            acc.z += __shfl_xor(acc.z, mm);
            acc.w += __shfl_xor(acc.w, mm);
        }
        int deg = end - beg;
        float inv = (deg > 0) ? (1.0f / (float)deg) : 0.f;
        if (sub == 0)
            *(float4*)&hn[nl][q * 4] =
                make_float4(acc.x * inv, acc.y * inv, acc.z * inv, acc.w * inv);
    }
    __syncthreads();

    // C: MLP — wave w, pass p: node w*8 + p*4 + sub
    #pragma unroll
    for (int p = 0; p < 2; ++p) {
        int nl = w * 8 + p * 4 + sub;
        int n  = nlo + nl;
        if (n < n_nodes) {
            const float* hrow = h + ((size_t)n << 6);
            float4 o = ((const float4*)bsh)[q];
            #pragma unroll
            for (int k4 = 0; k4 < 16; ++k4) {
                const float4 hq = *(const float4*)(hrow + k4 * 4);   // bcast x16
                #pragma unroll
                for (int c = 0; c < 4; ++c) {
                    float hv = (&hq.x)[c];
                    const float4 wv = *(const float4*)&Wsh[k4 * 4 + c][q * 4];
                    o.x = fmaf(hv, wv.x, o.x);
                    o.y = fmaf(hv, wv.y, o.y);
                    o.z = fmaf(hv, wv.z, o.z);
                    o.w = fmaf(hv, wv.w, o.w);
                }
            }
            #pragma unroll 16
            for (int k = 0; k < 64; ++k) {
                float hv = hn[nl][k];
                const float4 wv = *(const float4*)&Wsh[64 + k][q * 4];
                o.x = fmaf(hv, wv.x, o.x);
                o.y = fmaf(hv, wv.y, o.y);
                o.z = fmaf(hv, wv.z, o.z);
                o.w = fmaf(hv, wv.w, o.w);
            }
            *(float4*)(out + ((size_t)n << 6) + q * 4) = o;
        }
    }
}

extern "C" void kernel_launch(void* const* d_in, const int* in_sizes, int n_in,
                              void* d_out, int out_size, void* d_ws, size_t ws_size,
                              hipStream_t stream) {
    const float* h   = (const float*)d_in[0];
    const int*   src = (const int*)d_in[1];
    const int*   dst = (const int*)d_in[2];
    const float* W   = (const float*)d_in[3];
    const float* b   = (const float*)d_in[4];
    float* out = (float*)d_out;

    const int n_nodes = in_sizes[0] / IN_FEAT;
    const int n_edges = in_sizes[1];
    const int K  = (n_nodes + BKN - 1) >> KB_SHIFT;    // 782
    const int n4 = n_nodes * (IN_FEAT / 4);            // 800000 float4s

    // ws: hb[N*64 ushort] | pairs[K*CAP u32] | cursorG[K]
    unsigned short* hb = (unsigned short*)d_ws;
    unsigned* pairs    = (unsigned*)(hb + (size_t)n_nodes * IN_FEAT);
    int* cursorG       = (int*)(pairs + (size_t)K * CAP);

    hipMemsetAsync(cursorG, 0, (size_t)K * sizeof(int), stream);

    const int conv_tiles   = (n4 + 8191) / 8192;       // 98
    const int bucket_tiles = (n_edges + 8191) / 8192;  // 98
    sage_prep<<<conv_tiles + bucket_tiles, 256, 0, stream>>>(
        h, src, dst, hb, pairs, cursorG, n4, n_edges, conv_tiles, K);
    sage_fused<<<K, 512, 0, stream>>>(hb, h, pairs, cursorG, W, b, out, n_nodes);
}

// Round 9
// 133.322 us; speedup vs baseline: 1.1475x; 1.1475x over previous
//
#include <hip/hip_runtime.h>

// SAGEConv: h[50000,64] f32, src/dst[800000] int32, W[128,64] f32, b[64] f32
// out = concat(h, mean_{in-edges}(h[src])) @ W + b
//
// R9: 3 GPU ops (memset 3KB, prep, fused). vs R8:
//  - prep: rank captured from pass-1 LDS atomicAdd return (rnk pass deleted,
//    800k fewer ds-RMW), 512-thread tiles.
//  - fused: hn stored bf16 (LDS 59.9->50.4KB -> 3 blocks/CU, 24 waves),
//    rank-capture CSR build (half the LDS atomics), 4-deep gather unroll
//    (16 edges in flight/wave ~ mean degree).
//  R6 lesson: read-side shfl reduction, never feature-wise write atomics.

#define IN_FEAT 64
#define KB_SHIFT 6            // 64 nodes per bucket
#define BKN 64
#define CAP 2048              // pairs per bucket (mean 1024 at E=800k,K=782)
#define KMAX 1024             // supports n_nodes <= 65536

__device__ __forceinline__ unsigned short f2bf(float f) {
    unsigned u = __float_as_uint(f);
    return (unsigned short)((u + 0x7FFFu + ((u >> 16) & 1u)) >> 16);
}
__device__ __forceinline__ float bf2f(unsigned short s) {
    return __uint_as_float(((unsigned)s) << 16);
}

// ---- k1: blocks [0,conv_tiles): h->bf16 ; rest: bucket the edges -----------
__global__ __launch_bounds__(512) void sage_prep(
    const float* __restrict__ h, const int* __restrict__ src,
    const int* __restrict__ dst,
    unsigned short* __restrict__ hb, unsigned* __restrict__ pairs,
    int* __restrict__ cursorG,
    int n4, int n_edges, int conv_tiles, int K)
{
    __shared__ int cnt[KMAX];
    __shared__ int base[KMAX];
    int t = (int)threadIdx.x;

    if ((int)blockIdx.x < conv_tiles) {
        int tb = blockIdx.x * 8192;
        #pragma unroll
        for (int i = 0; i < 16; ++i) {
            int idx = tb + t + i * 512;            // float4 index
            if (idx < n4) {
                float4 v = ((const float4*)h)[idx];
                ushort4 r;
                r.x = f2bf(v.x); r.y = f2bf(v.y);
                r.z = f2bf(v.z); r.w = f2bf(v.w);
                ((ushort4*)hb)[idx] = r;
            }
        }
    } else {
        for (int k = t; k < K; k += 512) cnt[k] = 0;
        __syncthreads();
        int tb = ((int)blockIdx.x - conv_tiles) * 8192;
        int kb[16]; unsigned pk[16]; int rk[16];
        #pragma unroll 4
        for (int i = 0; i < 16; ++i) {
            int e = tb + t + i * 512;
            kb[i] = -1;
            if (e < n_edges) {
                int d = dst[e], s = src[e];
                int k = d >> KB_SHIFT;
                kb[i] = k;
                pk[i] = ((unsigned)s << KB_SHIFT) | (unsigned)(d & (BKN - 1));
                rk[i] = atomicAdd(&cnt[k], 1);     // rank within (tile,bucket)
            }
        }
        __syncthreads();
        for (int k = t; k < K; k += 512) {
            int c = cnt[k];
            base[k] = c ? atomicAdd(&cursorG[k], c) : 0;
        }
        __syncthreads();
        #pragma unroll 4
        for (int i = 0; i < 16; ++i) {
            if (kb[i] >= 0) {
                int pos = base[kb[i]] + rk[i];
                if (pos < CAP)                      // safety clamp
                    pairs[((size_t)kb[i] << 11) + pos] = pk[i];
            }
        }
    }
}

// ---- k2: per-bucket local CSR + gather-mean + MLP --------------------------
// One block (512 thr, 8 waves) per 64-node bucket. LDS ~50.4KB -> 3 blk/CU.
//  A: CSR in LDS, rank captured from the count atomic (single atomic pass).
//  B: wave w gathers nodes w*8..w*8+7: 16 lanes/edge x bf16x4 rows, 4-deep
//     unroll (16 edges in flight), __shfl_xor(16,32) reduce, mean -> bf16 hn.
//  C: MLP: wave w, pass p: node w*8+p*4+sub, cols 4q..4q+3; self row f32
//     global (broadcast), W rows ds_read_b128 shared by 4 nodes.
__global__ __launch_bounds__(512, 6) void sage_fused(
    const unsigned short* __restrict__ hb,
    const float* __restrict__ h,
    const unsigned* __restrict__ pairs,
    const int* __restrict__ cursorG,
    const float* __restrict__ W,     // [128,64] row-major
    const float* __restrict__ bias,
    float* __restrict__ out,
    int n_nodes)
{
    __shared__ float Wsh[128][64];        // 32 KB
    __shared__ float bsh[64];
    __shared__ unsigned short hn[BKN][68];// 8.7 KB (bf16 means)
    __shared__ int   list[CAP];           // 8 KB
    __shared__ int   cnt[BKN];
    __shared__ int   rs[BKN + 1];

    const int t = (int)threadIdx.x;
    {   // stage W: 2048 float4s, 4 per thread
        float4* wd = (float4*)&Wsh[0][0];
        const float4* wsv = (const float4*)W;
        wd[t]        = wsv[t];
        wd[t + 512]  = wsv[t + 512];
        wd[t + 1024] = wsv[t + 1024];
        wd[t + 1536] = wsv[t + 1536];
    }
    if (t < 64) { bsh[t] = bias[t]; cnt[t] = 0; }
    __syncthreads();

    const int b   = (int)blockIdx.x;
    const int nlo = b << KB_SHIFT;
    int m = cursorG[b]; if (m > CAP) m = CAP;
    const unsigned* pb = pairs + ((size_t)b << 11);

    // A: single-atomic-pass local CSR
    unsigned lp[4]; int lr[4];
    #pragma unroll
    for (int i = 0; i < 4; ++i) {
        int idx = t + i * 512;
        lr[i] = -1;
        if (idx < m) {
            lp[i] = pb[idx];
            lr[i] = atomicAdd(&cnt[lp[i] & (BKN - 1)], 1);
        }
    }
    __syncthreads();
    if (t < 64) {            // wave 0 scans the 64 counters
        int v = cnt[t];
        int incl = v;
        #pragma unroll
        for (int off = 1; off < 64; off <<= 1) {
            int x = __shfl_up(incl, off);
            if (t >= off) incl += x;
        }
        rs[t] = incl - v;
        if (t == 63) rs[64] = incl;
    }
    __syncthreads();
    #pragma unroll
    for (int i = 0; i < 4; ++i)
        if (lr[i] >= 0)
            list[rs[lp[i] & (BKN - 1)] + lr[i]] = (int)(lp[i] >> KB_SHIFT);
    __syncthreads();

    const int w    = t >> 6;
    const int lane = t & 63;
    const int sub  = lane >> 4;
    const int q    = lane & 15;

    // B: gather — wave w owns nodes w*8..w*8+7
    for (int i = 0; i < 8; ++i) {
        int nl = w * 8 + i;
        int n  = nlo + nl;
        if (n >= n_nodes) break;               // wave-uniform
        int beg = rs[nl], end = rs[nl + 1];
        float4 acc = make_float4(0.f, 0.f, 0.f, 0.f);
        int e = beg + sub;
        for (; e + 12 < end; e += 16) {        // 4 edges in flight per lane
            int s0 = list[e], s1 = list[e + 4], s2 = list[e + 8], s3 = list[e + 12];
            const ushort4 u0 = *(const ushort4*)(hb + ((size_t)s0 << 6) + q * 4);
            const ushort4 u1 = *(const ushort4*)(hb + ((size_t)s1 << 6) + q * 4);
            const ushort4 u2 = *(const ushort4*)(hb + ((size_t)s2 << 6) + q * 4);
            const ushort4 u3 = *(const ushort4*)(hb + ((size_t)s3 << 6) + q * 4);
            acc.x += (bf2f(u0.x) + bf2f(u1.x)) + (bf2f(u2.x) + bf2f(u3.x));
            acc.y += (bf2f(u0.y) + bf2f(u1.y)) + (bf2f(u2.y) + bf2f(u3.y));
            acc.z += (bf2f(u0.z) + bf2f(u1.z)) + (bf2f(u2.z) + bf2f(u3.z));
            acc.w += (bf2f(u0.w) + bf2f(u1.w)) + (bf2f(u2.w) + bf2f(u3.w));
        }
        for (; e + 4 < end; e += 8) {
            int s0 = list[e], s1 = list[e + 4];
            const ushort4 u0 = *(const ushort4*)(hb + ((size_t)s0 << 6) + q * 4);
            const ushort4 u1 = *(const ushort4*)(hb + ((size_t)s1 << 6) + q * 4);
            acc.x += bf2f(u0.x) + bf2f(u1.x);
            acc.y += bf2f(u0.y) + bf2f(u1.y);
            acc.z += bf2f(u0.z) + bf2f(u1.z);
            acc.w += bf2f(u0.w) + bf2f(u1.w);
        }
        if (e < end) {
            int s0 = list[e];
            const ushort4 u0 = *(const ushort4*)(hb + ((size_t)s0 << 6) + q * 4);
            acc.x += bf2f(u0.x); acc.y += bf2f(u0.y);
            acc.z += bf2f(u0.z); acc.w += bf2f(u0.w);
        }
        #pragma unroll
        for (int mm = 16; mm < 64; mm <<= 1) {
            acc.x += __shfl_xor(acc.x, mm);
            acc.y += __shfl_xor(acc.y, mm);
            acc.z += __shfl_xor(acc.z, mm);
            acc.w += __shfl_xor(acc.w, mm);
        }
        int deg = end - beg;
        float inv = (deg > 0) ? (1.0f / (float)deg) : 0.f;
        if (sub == 0) {
            ushort4 r;
            r.x = f2bf(acc.x * inv); r.y = f2bf(acc.y * inv);
            r.z = f2bf(acc.z * inv); r.w = f2bf(acc.w * inv);
            *(ushort4*)&hn[nl][q * 4] = r;
        }
    }
    __builtin_amdgcn_wave_barrier();   // hn is wave-private; scheduling fence

    // C: MLP — wave w, pass p: node w*8 + p*4 + sub
    #pragma unroll
    for (int p = 0; p < 2; ++p) {
        int nl = w * 8 + p * 4 + sub;
        int n  = nlo + nl;
        if (n < n_nodes) {
            const float* hrow = h + ((size_t)n << 6);
            float4 o = ((const float4*)bsh)[q];
            #pragma unroll
            for (int k4 = 0; k4 < 16; ++k4) {
                const float4 hq = *(const float4*)(hrow + k4 * 4);   // bcast x16
                #pragma unroll
                for (int c = 0; c < 4; ++c) {
                    float hv = (&hq.x)[c];
                    const float4 wv = *(const float4*)&Wsh[k4 * 4 + c][q * 4];
                    o.x = fmaf(hv, wv.x, o.x);
                    o.y = fmaf(hv, wv.y, o.y);
                    o.z = fmaf(hv, wv.z, o.z);
                    o.w = fmaf(hv, wv.w, o.w);
                }
            }
            #pragma unroll 16
            for (int k = 0; k < 64; ++k) {
                float hv = bf2f(hn[nl][k]);
                const float4 wv = *(const float4*)&Wsh[64 + k][q * 4];
                o.x = fmaf(hv, wv.x, o.x);
                o.y = fmaf(hv, wv.y, o.y);
                o.z = fmaf(hv, wv.z, o.z);
                o.w = fmaf(hv, wv.w, o.w);
            }
            *(float4*)(out + ((size_t)n << 6) + q * 4) = o;
        }
    }
}

extern "C" void kernel_launch(void* const* d_in, const int* in_sizes, int n_in,
                              void* d_out, int out_size, void* d_ws, size_t ws_size,
                              hipStream_t stream) {
    const float* h   = (const float*)d_in[0];
    const int*   src = (const int*)d_in[1];
    const int*   dst = (const int*)d_in[2];
    const float* W   = (const float*)d_in[3];
    const float* b   = (const float*)d_in[4];
    float* out = (float*)d_out;

    const int n_nodes = in_sizes[0] / IN_FEAT;
    const int n_edges = in_sizes[1];
    const int K  = (n_nodes + BKN - 1) >> KB_SHIFT;    // 782
    const int n4 = n_nodes * (IN_FEAT / 4);            // 800000 float4s

    // ws: hb[N*64 ushort] | pairs[K*CAP u32] | cursorG[K]
    unsigned short* hb = (unsigned short*)d_ws;
    unsigned* pairs    = (unsigned*)(hb + (size_t)n_nodes * IN_FEAT);
    int* cursorG       = (int*)(pairs + (size_t)K * CAP);

    hipMemsetAsync(cursorG, 0, (size_t)K * sizeof(int), stream);

    const int conv_tiles   = (n4 + 8191) / 8192;       // 98
    const int bucket_tiles = (n_edges + 8191) / 8192;  // 98
    sage_prep<<<conv_tiles + bucket_tiles, 512, 0, stream>>>(
        h, src, dst, hb, pairs, cursorG, n4, n_edges, conv_tiles, K);
    sage_fused<<<K, 512, 0, stream>>>(hb, h, pairs, cursorG, W, b, out, n_nodes);
}